// Round 2
// baseline (425.478 us; speedup 1.0000x reference)
//
#include <hip/hip_runtime.h>
#include <hip/hip_bf16.h>

#define BB 4
#define NN 2048
#define CC 768
#define HH 12
#define DD 64
#define MTOT (BB*NN)   // 8192

typedef __attribute__((ext_vector_type(8))) short frag16;   // 8 bf16 (4 VGPR)
typedef __attribute__((ext_vector_type(4))) float f32x4;

static __device__ __forceinline__ float bf2f(unsigned short u) {
  unsigned int x = ((unsigned int)u) << 16;
  return __builtin_bit_cast(float, x);
}
static __device__ __forceinline__ unsigned short f2bf(float f) {
  __hip_bfloat16 h = __float2bfloat16(f);
  return __builtin_bit_cast(unsigned short, h);
}
static __device__ __forceinline__ void gload16(const void* g, void* l) {
  __builtin_amdgcn_global_load_lds((const __attribute__((address_space(1))) void*)g,
                                   (__attribute__((address_space(3))) void*)l, 16, 0, 0);
}

// ---------------- dtype detector: is the input buffer fp32 (1) or bf16 (0)? ----
__global__ void detect_k(const unsigned short* x, int* flag) {
  __shared__ int cnt;
  if (threadIdx.x == 0) cnt = 0;
  __syncthreads();
  float v = bf2f(x[threadIdx.x]);
  float a = fabsf(v);
  int weird = (!(a <= 1e4f)) || (a != 0.0f && a < 1e-10f);
  if (weird) atomicAdd(&cnt, 1);
  __syncthreads();
  if (threadIdx.x == 0) *flag = (cnt >= 24) ? 1 : 0;
}

// ---------------- convert input -> canonical bf16 bits ------------------------
__global__ void conv_k(const void* __restrict__ src, unsigned short* __restrict__ dst,
                       int n, const int* __restrict__ flag) {
  int fp32 = *flag;
  int i0 = (blockIdx.x * blockDim.x + threadIdx.x) * 4;
  int stride = gridDim.x * blockDim.x * 4;
  if (fp32) {
    const float* s = (const float*)src;
    for (int i = i0; i < n; i += stride) {
      float4 v = *reinterpret_cast<const float4*>(&s[i]);
      ushort4 o;
      o.x = f2bf(v.x); o.y = f2bf(v.y); o.z = f2bf(v.z); o.w = f2bf(v.w);
      *reinterpret_cast<ushort4*>(&dst[i]) = o;
    }
  } else {
    const unsigned short* s = (const unsigned short*)src;
    for (int i = i0; i < n; i += stride)
      *reinterpret_cast<ushort4*>(&dst[i]) = *reinterpret_cast<const ushort4*>(&s[i]);
  }
}

// ---------------- GEMM C = A * B^T (A[M,K] row-major, B[F,K] row-major) -------
// 128x128 tile, BK=32, 4 waves in 2x2, each wave 64x64 (4x4 of 16x16x32 mfma).
// EPI=0: scatter to qkv: Q,K planes [b][h][n][d]; V plane TRANSPOSED [b][h][d][n].
// EPI=1: write out[M,CC] (dtype by flag).
template<int EPI>
__global__ __launch_bounds__(256) void gemm_bt(const unsigned short* __restrict__ A,
                                               const unsigned short* __restrict__ Bw,
                                               unsigned short* __restrict__ qkvbuf,
                                               void* __restrict__ outp,
                                               const int* __restrict__ flag) {
  constexpr int K = CC;
  __shared__ unsigned short Asm[128 * 32];
  __shared__ unsigned short Bsm[128 * 32];
  const int tid = threadIdx.x;
  const int lane = tid & 63;
  const int w = tid >> 6;
  const int wm = w >> 1, wn = w & 1;
  const int l15 = lane & 15;
  const int g = lane >> 4;
  const int m0 = blockIdx.x * 128;
  const int f0 = blockIdx.y * 128;

  f32x4 acc[4][4];
#pragma unroll
  for (int i = 0; i < 4; ++i)
#pragma unroll
    for (int j = 0; j < 4; ++j) acc[i][j] = (f32x4){0.f, 0.f, 0.f, 0.f};

  const unsigned short* Abase = A + (size_t)m0 * K;
  const unsigned short* Bbase = Bw + (size_t)f0 * K;

  for (int kt = 0; kt < K / 32; ++kt) {
    const int k0 = kt * 32;
    __syncthreads();
#pragma unroll
    for (int i = 0; i < 2; ++i) {
      int chunk = (i * 4 + w) * 64 + lane;
      int row = chunk >> 2;
      int col = (chunk & 3) << 3;
      gload16(Abase + (size_t)row * K + k0 + col, (char*)Asm + (i * 4 + w) * 1024);
      gload16(Bbase + (size_t)row * K + k0 + col, (char*)Bsm + (i * 4 + w) * 1024);
    }
    __syncthreads();

    frag16 af[4], bfv[4];
#pragma unroll
    for (int t = 0; t < 4; ++t) {
      af[t]  = *reinterpret_cast<const frag16*>(&Asm[(wm * 64 + t * 16 + l15) * 32 + 8 * g]);
      bfv[t] = *reinterpret_cast<const frag16*>(&Bsm[(wn * 64 + t * 16 + l15) * 32 + 8 * g]);
    }
#pragma unroll
    for (int i = 0; i < 4; ++i)
#pragma unroll
      for (int j = 0; j < 4; ++j)
        acc[i][j] = __builtin_amdgcn_mfma_f32_16x16x32_bf16(af[i], bfv[j], acc[i][j], 0, 0, 0);
  }

  if constexpr (EPI == 0) {
    const size_t plane = (size_t)BB * HH * NN * DD;
#pragma unroll
    for (int i = 0; i < 4; ++i) {
      int mbase = m0 + wm * 64 + i * 16 + 4 * g;
#pragma unroll
      for (int j = 0; j < 4; ++j) {
        int f = f0 + wn * 64 + j * 16 + l15;
        int which = f / CC;
        int rem = f - which * CC;
        int h = rem >> 6, d = rem & 63;
        if (which == 2) {
          // V plane transposed: [b][h][d][n]; r -> consecutive n -> pack 8B store
          int b = mbase >> 11, n = mbase & 2047;
          ushort4 o;
#pragma unroll
          for (int r = 0; r < 4; ++r) ((unsigned short*)&o)[r] = f2bf(acc[i][j][r]);
          size_t idx = 2 * plane + (((size_t)(b * HH + h) * DD + d) * NN + n);
          *reinterpret_cast<ushort4*>(&qkvbuf[idx]) = o;
        } else {
#pragma unroll
          for (int r = 0; r < 4; ++r) {
            int mm = mbase + r;
            int b = mm >> 11, n = mm & 2047;
            size_t idx = (size_t)which * plane + (((size_t)(b * HH + h) * NN + n) * DD + d);
            qkvbuf[idx] = f2bf(acc[i][j][r]);
          }
        }
      }
    }
  } else {
    int fp32 = *flag;
#pragma unroll
    for (int i = 0; i < 4; ++i) {
      int mbase = m0 + wm * 64 + i * 16 + 4 * g;
#pragma unroll
      for (int j = 0; j < 4; ++j) {
        int f = f0 + wn * 64 + j * 16 + l15;
#pragma unroll
        for (int r = 0; r < 4; ++r) {
          size_t idx = (size_t)(mbase + r) * CC + f;
          if (fp32) ((float*)outp)[idx] = acc[i][j][r];
          else ((unsigned short*)outp)[idx] = f2bf(acc[i][j][r]);
        }
      }
    }
  }
}

// ---------------- flash attention: no K/V LDS staging, zero barriers ----------
// K plane is [n][d] (contiguous d = MFMA k-dim for QK^T B-frag: direct global).
// V plane is [d][n] (contiguous n = MFMA k-dim for PV B-frag: direct global).
// Both planes (256 KB each per bh) are L2-resident; XCD swizzle keeps each
// XCD on ~6 contiguous bh planes. P handoff via wave-private LDS strip (no
// barrier needed; same-wave lgkmcnt ordering).
__global__ __launch_bounds__(256) void attn_k(const unsigned short* __restrict__ qkv,
                                              unsigned short* __restrict__ ctx) {
  __shared__ unsigned short Pl[4][16 * 72];
  const int tid = threadIdx.x;
  const int lane = tid & 63;
  const int w = tid >> 6;
  const int l15 = lane & 15;
  const int g = lane >> 4;

  // bijective XCD swizzle: nwg = 32*48 = 1536, 1536 % 8 == 0, cpx = 192
  int orig = blockIdx.x;
  int wgid = (orig & 7) * 192 + (orig >> 3);
  const int q0 = (wgid & 31) * 64;   // q-tile (fast dim -> same bh contiguous)
  const int bh = wgid >> 5;

  const size_t plane = (size_t)BB * HH * NN * DD;
  const unsigned short* Qg = qkv + (size_t)bh * NN * DD;
  const unsigned short* Kg = qkv + plane + (size_t)bh * NN * DD;
  const unsigned short* Vt = qkv + 2 * plane + (size_t)bh * NN * DD;  // [d][n]

  // Q fragments for this wave's 16-row strip (A-operand; k-dim = d)
  frag16 aq[2];
  {
    int qrow = q0 + w * 16 + l15;
    aq[0] = *reinterpret_cast<const frag16*>(&Qg[(size_t)qrow * DD + 8 * g]);
    aq[1] = *reinterpret_cast<const frag16*>(&Qg[(size_t)qrow * DD + 32 + 8 * g]);
  }

  f32x4 acc[4];
#pragma unroll
  for (int t = 0; t < 4; ++t) acc[t] = (f32x4){0.f, 0.f, 0.f, 0.f};
  float mrun[4] = {-INFINITY, -INFINITY, -INFINITY, -INFINITY};
  float lrun[4] = {0.f, 0.f, 0.f, 0.f};

  unsigned short* Pw = &Pl[w][0];
  const float SCALE2 = 0.18033688011112042f;   // (1/8) * log2(e); softmax in base-2

  for (int kv = 0; kv < NN / 64; ++kv) {
    const int n0 = kv * 64;

    // S2 = (Q K^T) * SCALE2 : B-frags straight from global (L2-hit)
    f32x4 sc[4];
#pragma unroll
    for (int t = 0; t < 4; ++t) sc[t] = (f32x4){0.f, 0.f, 0.f, 0.f};
#pragma unroll
    for (int ks = 0; ks < 2; ++ks) {
#pragma unroll
      for (int t = 0; t < 4; ++t) {
        frag16 kb = *reinterpret_cast<const frag16*>(
            &Kg[(size_t)(n0 + t * 16 + l15) * DD + ks * 32 + 8 * g]);
        sc[t] = __builtin_amdgcn_mfma_f32_16x16x32_bf16(aq[ks], kb, sc[t], 0, 0, 0);
      }
    }
#pragma unroll
    for (int t = 0; t < 4; ++t) sc[t] *= SCALE2;

    // online softmax (base-2) over 16-lane groups
    float mnew[4], corr[4], rs[4];
#pragma unroll
    for (int r = 0; r < 4; ++r) {
      float v = fmaxf(fmaxf(sc[0][r], sc[1][r]), fmaxf(sc[2][r], sc[3][r]));
      v = fmaxf(v, __shfl_xor(v, 1));
      v = fmaxf(v, __shfl_xor(v, 2));
      v = fmaxf(v, __shfl_xor(v, 4));
      v = fmaxf(v, __shfl_xor(v, 8));
      mnew[r] = fmaxf(mrun[r], v);
      corr[r] = __builtin_amdgcn_exp2f(mrun[r] - mnew[r]);
      mrun[r] = mnew[r];
      rs[r] = 0.f;
    }
#pragma unroll
    for (int t = 0; t < 4; ++t)
#pragma unroll
      for (int r = 0; r < 4; ++r) {
        float p = __builtin_amdgcn_exp2f(sc[t][r] - mnew[r]);
        sc[t][r] = p;
        rs[r] += p;
      }
#pragma unroll
    for (int r = 0; r < 4; ++r) {
      float s = rs[r];
      s += __shfl_xor(s, 1);
      s += __shfl_xor(s, 2);
      s += __shfl_xor(s, 4);
      s += __shfl_xor(s, 8);
      lrun[r] = lrun[r] * corr[r] + s;
#pragma unroll
      for (int t = 0; t < 4; ++t) acc[t][r] *= corr[r];
    }

    // P -> bf16 in wave-private LDS strip (no barrier: same-wave ordering)
#pragma unroll
    for (int t = 0; t < 4; ++t)
#pragma unroll
      for (int r = 0; r < 4; ++r)
        Pw[(4 * g + r) * 72 + t * 16 + l15] = f2bf(sc[t][r]);

    // acc += P * V : A = P rows from LDS, B = V^T rows straight from global
#pragma unroll
    for (int ks = 0; ks < 2; ++ks) {
      frag16 pa = *reinterpret_cast<const frag16*>(&Pw[l15 * 72 + ks * 32 + 8 * g]);
#pragma unroll
      for (int t = 0; t < 4; ++t) {
        frag16 vb = *reinterpret_cast<const frag16*>(
            &Vt[(size_t)(t * 16 + l15) * NN + n0 + ks * 32 + 8 * g]);
        acc[t] = __builtin_amdgcn_mfma_f32_16x16x32_bf16(pa, vb, acc[t], 0, 0, 0);
      }
    }
  }

  // epilogue: ctx[b*N+q][h*64+d], normalized
  const int b = bh / HH, h = bh - b * HH;
#pragma unroll
  for (int r = 0; r < 4; ++r) {
    int qn = q0 + w * 16 + 4 * g + r;
    float inv = 1.0f / lrun[r];
#pragma unroll
    for (int t = 0; t < 4; ++t) {
      int d = t * 16 + l15;
      ctx[((size_t)(b * NN + qn)) * CC + h * DD + d] = f2bf(acc[t][r] * inv);
    }
  }
}

// ------------------------------------------------------------------------------
extern "C" void kernel_launch(void* const* d_in, const int* in_sizes, int n_in,
                              void* d_out, int out_size, void* d_ws, size_t ws_size,
                              hipStream_t stream) {
  const void* x = d_in[0];
  const void* qw = d_in[1];
  const void* pw = d_in[2];
  char* ws = (char*)d_ws;
  int* flag = (int*)ws;
  size_t off = 256;
  unsigned short* xb = (unsigned short*)(ws + off); off += (size_t)MTOT * CC * 2;   // reused as ctx
  unsigned short* qwb = (unsigned short*)(ws + off); off += (size_t)3 * CC * CC * 2;
  unsigned short* pwb = (unsigned short*)(ws + off); off += (size_t)CC * CC * 2;
  unsigned short* qkvbuf = (unsigned short*)(ws + off); off += (size_t)3 * MTOT * CC * 2;
  unsigned short* ctx = xb;  // x is consumed by QKV GEMM before attention writes ctx

  detect_k<<<1, 256, 0, stream>>>((const unsigned short*)x, flag);
  conv_k<<<1024, 256, 0, stream>>>(x, xb, MTOT * CC, flag);
  conv_k<<<512, 256, 0, stream>>>(qw, qwb, 3 * CC * CC, flag);
  conv_k<<<256, 256, 0, stream>>>(pw, pwb, CC * CC, flag);
  gemm_bt<0><<<dim3(MTOT / 128, (3 * CC) / 128), 256, 0, stream>>>(xb, qwb, qkvbuf, nullptr, flag);
  attn_k<<<1536, 256, 0, stream>>>(qkvbuf, ctx);
  gemm_bt<1><<<dim3(MTOT / 128, CC / 128), 256, 0, stream>>>(ctx, pwb, nullptr, d_out, flag);
}

// Round 3
// 252.204 us; speedup vs baseline: 1.6870x; 1.6870x over previous
//
#include <hip/hip_runtime.h>
#include <hip/hip_bf16.h>

#define BB 4
#define NN 2048
#define CC 768
#define HH 12
#define DD 64
#define MTOT (BB*NN)   // 8192

typedef __attribute__((ext_vector_type(8))) short frag16;   // 8 bf16 (4 VGPR)
typedef __attribute__((ext_vector_type(4))) float f32x4;

static __device__ __forceinline__ float bf2f(unsigned short u) {
  unsigned int x = ((unsigned int)u) << 16;
  return __builtin_bit_cast(float, x);
}
static __device__ __forceinline__ unsigned short f2bf(float f) {
  __hip_bfloat16 h = __float2bfloat16(f);
  return __builtin_bit_cast(unsigned short, h);
}
static __device__ __forceinline__ void gload16(const void* g, void* l) {
  __builtin_amdgcn_global_load_lds((const __attribute__((address_space(1))) void*)g,
                                   (__attribute__((address_space(3))) void*)l, 16, 0, 0);
}

// ---------------- dtype detector: is the input buffer fp32 (1) or bf16 (0)? ----
__global__ void detect_k(const unsigned short* x, int* flag) {
  __shared__ int cnt;
  if (threadIdx.x == 0) cnt = 0;
  __syncthreads();
  float v = bf2f(x[threadIdx.x]);
  float a = fabsf(v);
  int weird = (!(a <= 1e4f)) || (a != 0.0f && a < 1e-10f);
  if (weird) atomicAdd(&cnt, 1);
  __syncthreads();
  if (threadIdx.x == 0) *flag = (cnt >= 24) ? 1 : 0;
}

// ---------------- convert input -> canonical bf16 bits ------------------------
__global__ void conv_k(const void* __restrict__ src, unsigned short* __restrict__ dst,
                       int n, const int* __restrict__ flag) {
  int fp32 = *flag;
  int i0 = (blockIdx.x * blockDim.x + threadIdx.x) * 4;
  int stride = gridDim.x * blockDim.x * 4;
  if (fp32) {
    const float* s = (const float*)src;
    for (int i = i0; i < n; i += stride) {
      float4 v = *reinterpret_cast<const float4*>(&s[i]);
      ushort4 o;
      o.x = f2bf(v.x); o.y = f2bf(v.y); o.z = f2bf(v.z); o.w = f2bf(v.w);
      *reinterpret_cast<ushort4*>(&dst[i]) = o;
    }
  } else {
    const unsigned short* s = (const unsigned short*)src;
    for (int i = i0; i < n; i += stride)
      *reinterpret_cast<ushort4*>(&dst[i]) = *reinterpret_cast<const ushort4*>(&s[i]);
  }
}

// ---------------- GEMM C = A * B^T (A[M,K] row-major, B[F,K] row-major) -------
// EPI=0: scatter to qkv:
//   Q plane [b][h][n][d] (plain)
//   K plane [b][h][n][d] with d pre-swizzled: d' = d ^ ((n&7)<<3)
//   V plane TRANSPOSED [b][h][d][n] with n pre-swizzled within 64-blocks:
//     n' = (n&~63) | ((n&63) ^ ((d&7)<<3))
// so attention can stage both with linear global_load_lds and read
// ds_read_b128 frags via the same XOR (conflict-free).
// EPI=1: write out[M,CC] (dtype by flag).
template<int EPI>
__global__ __launch_bounds__(256) void gemm_bt(const unsigned short* __restrict__ A,
                                               const unsigned short* __restrict__ Bw,
                                               unsigned short* __restrict__ qkvbuf,
                                               void* __restrict__ outp,
                                               const int* __restrict__ flag) {
  constexpr int K = CC;
  __shared__ unsigned short Asm[128 * 32];
  __shared__ unsigned short Bsm[128 * 32];
  const int tid = threadIdx.x;
  const int lane = tid & 63;
  const int w = tid >> 6;
  const int wm = w >> 1, wn = w & 1;
  const int l15 = lane & 15;
  const int g = lane >> 4;
  const int m0 = blockIdx.x * 128;
  const int f0 = blockIdx.y * 128;

  f32x4 acc[4][4];
#pragma unroll
  for (int i = 0; i < 4; ++i)
#pragma unroll
    for (int j = 0; j < 4; ++j) acc[i][j] = (f32x4){0.f, 0.f, 0.f, 0.f};

  const unsigned short* Abase = A + (size_t)m0 * K;
  const unsigned short* Bbase = Bw + (size_t)f0 * K;

  for (int kt = 0; kt < K / 32; ++kt) {
    const int k0 = kt * 32;
    __syncthreads();
#pragma unroll
    for (int i = 0; i < 2; ++i) {
      int chunk = (i * 4 + w) * 64 + lane;
      int row = chunk >> 2;
      int col = (chunk & 3) << 3;
      gload16(Abase + (size_t)row * K + k0 + col, (char*)Asm + (i * 4 + w) * 1024);
      gload16(Bbase + (size_t)row * K + k0 + col, (char*)Bsm + (i * 4 + w) * 1024);
    }
    __syncthreads();

    frag16 af[4], bfv[4];
#pragma unroll
    for (int t = 0; t < 4; ++t) {
      af[t]  = *reinterpret_cast<const frag16*>(&Asm[(wm * 64 + t * 16 + l15) * 32 + 8 * g]);
      bfv[t] = *reinterpret_cast<const frag16*>(&Bsm[(wn * 64 + t * 16 + l15) * 32 + 8 * g]);
    }
#pragma unroll
    for (int i = 0; i < 4; ++i)
#pragma unroll
      for (int j = 0; j < 4; ++j)
        acc[i][j] = __builtin_amdgcn_mfma_f32_16x16x32_bf16(af[i], bfv[j], acc[i][j], 0, 0, 0);
  }

  if constexpr (EPI == 0) {
    const size_t plane = (size_t)BB * HH * NN * DD;
#pragma unroll
    for (int i = 0; i < 4; ++i) {
      int mbase = m0 + wm * 64 + i * 16 + 4 * g;
#pragma unroll
      for (int j = 0; j < 4; ++j) {
        int f = f0 + wn * 64 + j * 16 + l15;
        int which = f / CC;
        int rem = f - which * CC;
        int h = rem >> 6, d = rem & 63;
        if (which == 2) {
          // V transposed + n-swizzled; r -> consecutive n -> pack 8B store
          int b = mbase >> 11, n = mbase & 2047;
          int nsw = (n & ~63) | ((n & 63) ^ ((d & 7) << 3));
          ushort4 o;
#pragma unroll
          for (int r = 0; r < 4; ++r) ((unsigned short*)&o)[r] = f2bf(acc[i][j][r]);
          size_t idx = 2 * plane + (((size_t)(b * HH + h) * DD + d) * NN + nsw);
          *reinterpret_cast<ushort4*>(&qkvbuf[idx]) = o;
        } else if (which == 1) {
#pragma unroll
          for (int r = 0; r < 4; ++r) {
            int mm = mbase + r;
            int b = mm >> 11, n = mm & 2047;
            int dsw = d ^ ((n & 7) << 3);
            size_t idx = plane + (((size_t)(b * HH + h) * NN + n) * DD + dsw);
            qkvbuf[idx] = f2bf(acc[i][j][r]);
          }
        } else {
#pragma unroll
          for (int r = 0; r < 4; ++r) {
            int mm = mbase + r;
            int b = mm >> 11, n = mm & 2047;
            size_t idx = (((size_t)(b * HH + h) * NN + n) * DD + d);
            qkvbuf[idx] = f2bf(acc[i][j][r]);
          }
        }
      }
    }
  } else {
    int fp32 = *flag;
#pragma unroll
    for (int i = 0; i < 4; ++i) {
      int mbase = m0 + wm * 64 + i * 16 + 4 * g;
#pragma unroll
      for (int j = 0; j < 4; ++j) {
        int f = f0 + wn * 64 + j * 16 + l15;
#pragma unroll
        for (int r = 0; r < 4; ++r) {
          size_t idx = (size_t)(mbase + r) * CC + f;
          if (fp32) ((float*)outp)[idx] = acc[i][j][r];
          else ((unsigned short*)outp)[idx] = f2bf(acc[i][j][r]);
        }
      }
    }
  }
}

// ---------------- flash attention ---------------------------------------------
// 128 q-rows/block (4 waves x 2 strips of 16), KV tile 64, double-buffered
// K/V staged via linear global_load_lds from pre-swizzled planes.
// One __syncthreads per KV tile (its vmcnt drain = the pipeline wait).
__global__ __launch_bounds__(256) void attn_k(const unsigned short* __restrict__ qkv,
                                              unsigned short* __restrict__ ctx) {
  __shared__ unsigned short Kb[2][64 * 64];
  __shared__ unsigned short Vb[2][64 * 64];
  __shared__ unsigned short Pl[4][32 * 72];
  const int tid = threadIdx.x;
  const int lane = tid & 63;
  const int w = tid >> 6;
  const int l15 = lane & 15;
  const int g = lane >> 4;
  const int lrow = lane >> 3;        // 0..7 (staging row within 8)
  const int lcol = (lane & 7) * 8;   // staging col (shorts)

  // bijective XCD swizzle: nwg = 16*48 = 768, 768 % 8 == 0, cpx = 96
  int orig = blockIdx.x;
  int wgid = (orig & 7) * 96 + (orig >> 3);
  const int q0 = (wgid & 15) * 128;
  const int bh = wgid >> 4;

  const size_t plane = (size_t)BB * HH * NN * DD;
  const unsigned short* Qg = qkv + (size_t)bh * NN * DD;
  const unsigned short* Kg = qkv + plane + (size_t)bh * NN * DD;      // swizzled [n][d]
  const unsigned short* Vt = qkv + 2 * plane + (size_t)bh * NN * DD;  // swizzled [d][n]

  // Q fragments: 2 strips of 16 rows per wave
  frag16 aq[2][2];
#pragma unroll
  for (int s = 0; s < 2; ++s) {
    int qrow = q0 + w * 32 + s * 16 + l15;
    aq[s][0] = *reinterpret_cast<const frag16*>(&Qg[(size_t)qrow * DD + 8 * g]);
    aq[s][1] = *reinterpret_cast<const frag16*>(&Qg[(size_t)qrow * DD + 32 + 8 * g]);
  }

  f32x4 acc[2][4];
  float mr[2][4], lr[2][4];
#pragma unroll
  for (int s = 0; s < 2; ++s)
#pragma unroll
    for (int t = 0; t < 4; ++t) {
      acc[s][t] = (f32x4){0.f, 0.f, 0.f, 0.f};
      mr[s][t] = -INFINITY;
      lr[s][t] = 0.f;
    }

  unsigned short* Pw = &Pl[w][0];
  const float SC = 0.18033688011112042f;   // (1/8) * log2(e)

#define STAGE(buf, n0)                                                              \
  {                                                                                 \
    _Pragma("unroll")                                                               \
    for (int i_ = 0; i_ < 2; ++i_) {                                                \
      int r_ = w * 16 + i_ * 8 + lrow;                                              \
      gload16(Kg + (size_t)((n0) + r_) * DD + lcol, &Kb[buf][w * 1024 + i_ * 512]); \
      gload16(Vt + (size_t)r_ * NN + (n0) + lcol, &Vb[buf][w * 1024 + i_ * 512]);   \
    }                                                                               \
  }

  int cur = 0;
  STAGE(0, 0)

  for (int kv = 0; kv < NN / 64; ++kv) {
    __syncthreads();   // drains vmcnt(0): buf[cur] ready; also fences buf reuse
    if (kv + 1 < NN / 64) STAGE(cur ^ 1, (kv + 1) * 64)

    // K fragments (hoisted across strips), conflict-free via XOR
    frag16 kb[2][4];
#pragma unroll
    for (int ks = 0; ks < 2; ++ks)
#pragma unroll
      for (int t = 0; t < 4; ++t) {
        int krow = t * 16 + l15;
        kb[ks][t] = *reinterpret_cast<const frag16*>(
            (const char*)&Kb[cur][0] + ((krow * 128 + ks * 64 + 16 * g) ^ ((krow & 7) << 4)));
      }

#pragma unroll
    for (int s = 0; s < 2; ++s) {
      f32x4 sc4[4];
#pragma unroll
      for (int t = 0; t < 4; ++t) sc4[t] = (f32x4){0.f, 0.f, 0.f, 0.f};
#pragma unroll
      for (int ks = 0; ks < 2; ++ks)
#pragma unroll
        for (int t = 0; t < 4; ++t)
          sc4[t] = __builtin_amdgcn_mfma_f32_16x16x32_bf16(aq[s][ks], kb[ks][t], sc4[t], 0, 0, 0);

      // online softmax in base-2 domain; scale folded into fma
      float mn[4], co[4], ms[4], rs[4];
#pragma unroll
      for (int r = 0; r < 4; ++r) {
        float v = fmaxf(fmaxf(sc4[0][r], sc4[1][r]), fmaxf(sc4[2][r], sc4[3][r]));
        v = fmaxf(v, __shfl_xor(v, 1));
        v = fmaxf(v, __shfl_xor(v, 2));
        v = fmaxf(v, __shfl_xor(v, 4));
        v = fmaxf(v, __shfl_xor(v, 8));
        mn[r] = fmaxf(mr[s][r], v);
        co[r] = __builtin_amdgcn_exp2f((mr[s][r] - mn[r]) * SC);
        mr[s][r] = mn[r];
        ms[r] = mn[r] * SC;
        rs[r] = 0.f;
      }
#pragma unroll
      for (int t = 0; t < 4; ++t)
#pragma unroll
        for (int r = 0; r < 4; ++r) {
          float p = __builtin_amdgcn_exp2f(__builtin_fmaf(sc4[t][r], SC, -ms[r]));
          sc4[t][r] = p;
          rs[r] += p;
        }
#pragma unroll
      for (int r = 0; r < 4; ++r) {
        float sm = rs[r];
        sm += __shfl_xor(sm, 1);
        sm += __shfl_xor(sm, 2);
        sm += __shfl_xor(sm, 4);
        sm += __shfl_xor(sm, 8);
        lr[s][r] = lr[s][r] * co[r] + sm;
#pragma unroll
        for (int t = 0; t < 4; ++t) acc[s][t][r] *= co[r];
      }
      // P strip -> LDS (wave-private; same-wave lgkmcnt ordering, no barrier)
#pragma unroll
      for (int t = 0; t < 4; ++t)
#pragma unroll
        for (int r = 0; r < 4; ++r)
          Pw[(s * 16 + 4 * g + r) * 72 + t * 16 + l15] = f2bf(sc4[t][r]);
    }

    // acc += P * V
#pragma unroll
    for (int ks = 0; ks < 2; ++ks) {
      frag16 vb[4];
#pragma unroll
      for (int t = 0; t < 4; ++t) {
        int vrow = t * 16 + l15;
        vb[t] = *reinterpret_cast<const frag16*>(
            (const char*)&Vb[cur][0] + ((vrow * 128 + ks * 64 + 16 * g) ^ ((vrow & 7) << 4)));
      }
#pragma unroll
      for (int s = 0; s < 2; ++s) {
        frag16 pa = *reinterpret_cast<const frag16*>(&Pw[(s * 16 + l15) * 72 + ks * 32 + 8 * g]);
#pragma unroll
        for (int t = 0; t < 4; ++t)
          acc[s][t] = __builtin_amdgcn_mfma_f32_16x16x32_bf16(pa, vb[t], acc[s][t], 0, 0, 0);
      }
    }
    cur ^= 1;
  }

  // epilogue: ctx[b*N+q][h*64+d], normalized
  const int b = bh / HH, h = bh - b * HH;
#pragma unroll
  for (int s = 0; s < 2; ++s)
#pragma unroll
    for (int r = 0; r < 4; ++r) {
      int qn = q0 + w * 32 + s * 16 + 4 * g + r;
      float inv = 1.0f / lr[s][r];
#pragma unroll
      for (int t = 0; t < 4; ++t) {
        int d = t * 16 + l15;
        ctx[((size_t)(b * NN + qn)) * CC + h * DD + d] = f2bf(acc[s][t][r] * inv);
      }
    }
#undef STAGE
}

// ------------------------------------------------------------------------------
extern "C" void kernel_launch(void* const* d_in, const int* in_sizes, int n_in,
                              void* d_out, int out_size, void* d_ws, size_t ws_size,
                              hipStream_t stream) {
  const void* x = d_in[0];
  const void* qw = d_in[1];
  const void* pw = d_in[2];
  char* ws = (char*)d_ws;
  int* flag = (int*)ws;
  size_t off = 256;
  unsigned short* xb = (unsigned short*)(ws + off); off += (size_t)MTOT * CC * 2;   // reused as ctx
  unsigned short* qwb = (unsigned short*)(ws + off); off += (size_t)3 * CC * CC * 2;
  unsigned short* pwb = (unsigned short*)(ws + off); off += (size_t)CC * CC * 2;
  unsigned short* qkvbuf = (unsigned short*)(ws + off); off += (size_t)3 * MTOT * CC * 2;
  unsigned short* ctx = xb;  // x is consumed by QKV GEMM before attention writes ctx

  detect_k<<<1, 256, 0, stream>>>((const unsigned short*)x, flag);
  conv_k<<<1024, 256, 0, stream>>>(x, xb, MTOT * CC, flag);
  conv_k<<<512, 256, 0, stream>>>(qw, qwb, 3 * CC * CC, flag);
  conv_k<<<256, 256, 0, stream>>>(pw, pwb, CC * CC, flag);
  gemm_bt<0><<<dim3(MTOT / 128, (3 * CC) / 128), 256, 0, stream>>>(xb, qwb, qkvbuf, nullptr, flag);
  attn_k<<<768, 256, 0, stream>>>(qkvbuf, ctx);
  gemm_bt<1><<<dim3(MTOT / 128, CC / 128), 256, 0, stream>>>(ctx, pwb, nullptr, d_out, flag);
}

// Round 4
// 189.466 us; speedup vs baseline: 2.2457x; 1.3311x over previous
//
#include <hip/hip_runtime.h>
#include <hip/hip_bf16.h>

#define BB 4
#define NN 2048
#define CC 768
#define HH 12
#define DD 64
#define MTOT (BB*NN)   // 8192

typedef __attribute__((ext_vector_type(8))) short frag16;    // 8 bf16 (4 VGPR)
typedef __attribute__((ext_vector_type(4))) float f32x4;
typedef __attribute__((ext_vector_type(16))) float f32x16;
typedef __attribute__((ext_vector_type(4))) unsigned int u32x4;

static __device__ __forceinline__ float bf2f(unsigned short u) {
  unsigned int x = ((unsigned int)u) << 16;
  return __builtin_bit_cast(float, x);
}
static __device__ __forceinline__ unsigned short f2bf(float f) {
  __hip_bfloat16 h = __float2bfloat16(f);
  return __builtin_bit_cast(unsigned short, h);
}
static __device__ __forceinline__ unsigned int cvt_pk_bf16(float lo, float hi) {
  unsigned int r;
  asm("v_cvt_pk_bf16_f32 %0, %1, %2" : "=v"(r) : "v"(lo), "v"(hi));
  return r;
}
static __device__ __forceinline__ void gload16(const void* g, void* l) {
  __builtin_amdgcn_global_load_lds((const __attribute__((address_space(1))) void*)g,
                                   (__attribute__((address_space(3))) void*)l, 16, 0, 0);
}

// ---------------- dtype detector: is the input buffer fp32 (1) or bf16 (0)? ----
__global__ void detect_k(const unsigned short* x, int* flag) {
  __shared__ int cnt;
  if (threadIdx.x == 0) cnt = 0;
  __syncthreads();
  float v = bf2f(x[threadIdx.x]);
  float a = fabsf(v);
  int weird = (!(a <= 1e4f)) || (a != 0.0f && a < 1e-10f);
  if (weird) atomicAdd(&cnt, 1);
  __syncthreads();
  if (threadIdx.x == 0) *flag = (cnt >= 24) ? 1 : 0;
}

// ---------------- convert input -> canonical bf16 bits ------------------------
__global__ void conv_k(const void* __restrict__ src, unsigned short* __restrict__ dst,
                       int n, const int* __restrict__ flag) {
  int fp32 = *flag;
  int i0 = (blockIdx.x * blockDim.x + threadIdx.x) * 4;
  int stride = gridDim.x * blockDim.x * 4;
  if (fp32) {
    const float* s = (const float*)src;
    for (int i = i0; i < n; i += stride) {
      float4 v = *reinterpret_cast<const float4*>(&s[i]);
      ushort4 o;
      o.x = f2bf(v.x); o.y = f2bf(v.y); o.z = f2bf(v.z); o.w = f2bf(v.w);
      *reinterpret_cast<ushort4*>(&dst[i]) = o;
    }
  } else {
    const unsigned short* s = (const unsigned short*)src;
    for (int i = i0; i < n; i += stride)
      *reinterpret_cast<ushort4*>(&dst[i]) = *reinterpret_cast<const ushort4*>(&s[i]);
  }
}

// ---------------- GEMM C = A * B^T (A[M,K] row-major, B[F,K] row-major) -------
// EPI=0: scatter to qkv:
//   Q plane [b][h][n][d] (plain)
//   K plane [b][h][n][d] with d pre-swizzled: d' = d ^ ((n&7)<<3)
//   V plane TRANSPOSED [b][h][d][n], n pre-swizzled within 64-blocks:
//     n' = (n&~63) | ((n&63) ^ ((d&7)<<3))
// EPI=1: write out[M,CC] (dtype by flag).
template<int EPI>
__global__ __launch_bounds__(256) void gemm_bt(const unsigned short* __restrict__ A,
                                               const unsigned short* __restrict__ Bw,
                                               unsigned short* __restrict__ qkvbuf,
                                               void* __restrict__ outp,
                                               const int* __restrict__ flag) {
  constexpr int K = CC;
  __shared__ unsigned short Asm[128 * 32];
  __shared__ unsigned short Bsm[128 * 32];
  const int tid = threadIdx.x;
  const int lane = tid & 63;
  const int w = tid >> 6;
  const int wm = w >> 1, wn = w & 1;
  const int l15 = lane & 15;
  const int g = lane >> 4;
  const int m0 = blockIdx.x * 128;
  const int f0 = blockIdx.y * 128;

  f32x4 acc[4][4];
#pragma unroll
  for (int i = 0; i < 4; ++i)
#pragma unroll
    for (int j = 0; j < 4; ++j) acc[i][j] = (f32x4){0.f, 0.f, 0.f, 0.f};

  const unsigned short* Abase = A + (size_t)m0 * K;
  const unsigned short* Bbase = Bw + (size_t)f0 * K;

  for (int kt = 0; kt < K / 32; ++kt) {
    const int k0 = kt * 32;
    __syncthreads();
#pragma unroll
    for (int i = 0; i < 2; ++i) {
      int chunk = (i * 4 + w) * 64 + lane;
      int row = chunk >> 2;
      int col = (chunk & 3) << 3;
      gload16(Abase + (size_t)row * K + k0 + col, (char*)Asm + (i * 4 + w) * 1024);
      gload16(Bbase + (size_t)row * K + k0 + col, (char*)Bsm + (i * 4 + w) * 1024);
    }
    __syncthreads();

    frag16 af[4], bfv[4];
#pragma unroll
    for (int t = 0; t < 4; ++t) {
      af[t]  = *reinterpret_cast<const frag16*>(&Asm[(wm * 64 + t * 16 + l15) * 32 + 8 * g]);
      bfv[t] = *reinterpret_cast<const frag16*>(&Bsm[(wn * 64 + t * 16 + l15) * 32 + 8 * g]);
    }
#pragma unroll
    for (int i = 0; i < 4; ++i)
#pragma unroll
      for (int j = 0; j < 4; ++j)
        acc[i][j] = __builtin_amdgcn_mfma_f32_16x16x32_bf16(af[i], bfv[j], acc[i][j], 0, 0, 0);
  }

  if constexpr (EPI == 0) {
    const size_t plane = (size_t)BB * HH * NN * DD;
#pragma unroll
    for (int i = 0; i < 4; ++i) {
      int mbase = m0 + wm * 64 + i * 16 + 4 * g;
#pragma unroll
      for (int j = 0; j < 4; ++j) {
        int f = f0 + wn * 64 + j * 16 + l15;
        int which = f / CC;
        int rem = f - which * CC;
        int h = rem >> 6, d = rem & 63;
        if (which == 2) {
          int b = mbase >> 11, n = mbase & 2047;
          int nsw = (n & ~63) | ((n & 63) ^ ((d & 7) << 3));
          ushort4 o;
#pragma unroll
          for (int r = 0; r < 4; ++r) ((unsigned short*)&o)[r] = f2bf(acc[i][j][r]);
          size_t idx = 2 * plane + (((size_t)(b * HH + h) * DD + d) * NN + nsw);
          *reinterpret_cast<ushort4*>(&qkvbuf[idx]) = o;
        } else if (which == 1) {
#pragma unroll
          for (int r = 0; r < 4; ++r) {
            int mm = mbase + r;
            int b = mm >> 11, n = mm & 2047;
            int dsw = d ^ ((n & 7) << 3);
            size_t idx = plane + (((size_t)(b * HH + h) * NN + n) * DD + dsw);
            qkvbuf[idx] = f2bf(acc[i][j][r]);
          }
        } else {
#pragma unroll
          for (int r = 0; r < 4; ++r) {
            int mm = mbase + r;
            int b = mm >> 11, n = mm & 2047;
            size_t idx = (((size_t)(b * HH + h) * NN + n) * DD + d);
            qkvbuf[idx] = f2bf(acc[i][j][r]);
          }
        }
      }
    }
  } else {
    int fp32 = *flag;
#pragma unroll
    for (int i = 0; i < 4; ++i) {
      int mbase = m0 + wm * 64 + i * 16 + 4 * g;
#pragma unroll
      for (int j = 0; j < 4; ++j) {
        int f = f0 + wn * 64 + j * 16 + l15;
#pragma unroll
        for (int r = 0; r < 4; ++r) {
          size_t idx = (size_t)(mbase + r) * CC + f;
          if (fp32) ((float*)outp)[idx] = acc[i][j][r];
          else ((unsigned short*)outp)[idx] = f2bf(acc[i][j][r]);
        }
      }
    }
  }
}

// ---------------- flash attention: swapped-QK^T 32x32, in-register softmax ----
// 4 waves x 32 q-rows = 128 q/block, KV tile 64 (2 subtiles of 32), dbuf LDS.
// mfma_32x32x16(A=K,B=Q) -> D[row=kv][col=q]: lane owns q=lane&31, 16 kv in
// regs (kv(r)=(r&3)+8*(r>>2)+4*hl, hl=lane>>5); other 16 kv in lane^32.
// Softmax: in-reg trees + one shfl_xor(32). P stays in registers:
// cvt_pk_bf16 pairs -> shfl_xor(32) -> select -> PV A-frags. No P LDS.
__global__ __launch_bounds__(256) void attn_k(const unsigned short* __restrict__ qkv,
                                              unsigned short* __restrict__ ctx) {
  __shared__ unsigned short Kb[2][64 * 64];
  __shared__ unsigned short Vb[2][64 * 64];
  const int tid = threadIdx.x;
  const int lane = tid & 63;
  const int w = tid >> 6;
  const int l31 = lane & 31;
  const int hl = lane >> 5;
  const int lrow = lane >> 3;        // staging row within 8
  const int lcol = (lane & 7) * 8;   // staging col (shorts)

  // bijective XCD swizzle: nwg = 16*48 = 768, 768 % 8 == 0, cpx = 96
  int orig = blockIdx.x;
  int wgid = (orig & 7) * 96 + (orig >> 3);
  const int q0 = (wgid & 15) * 128;
  const int bh = wgid >> 4;

  const size_t plane = (size_t)BB * HH * NN * DD;
  const unsigned short* Qg = qkv + (size_t)bh * NN * DD;
  const unsigned short* Kg = qkv + plane + (size_t)bh * NN * DD;      // swizzled [n][d]
  const unsigned short* Vt = qkv + 2 * plane + (size_t)bh * NN * DD;  // swizzled [d][n]

  // Q B-fragments: lane holds Q[q=lane&31 of wave strip][d = slab*16 + hl*8 + j]
  frag16 qb[4];
  {
    int qrow = q0 + w * 32 + l31;
#pragma unroll
    for (int s = 0; s < 4; ++s)
      qb[s] = *reinterpret_cast<const frag16*>(&Qg[(size_t)qrow * DD + s * 16 + hl * 8]);
  }

  f32x16 acc0, acc1;
#pragma unroll
  for (int i = 0; i < 16; ++i) { acc0[i] = 0.f; acc1[i] = 0.f; }
  float m2 = -1e30f;   // running max in exp2-domain (finite: avoids inf-inf NaN)
  float lsum = 0.f;
  const float SC = 0.18033688011112042f;   // (1/8) * log2(e)
  const float THR2 = 10.0f;                // defer-max threshold (exp2 domain)

#define STAGE(buf, n0)                                                              \
  {                                                                                 \
    _Pragma("unroll")                                                               \
    for (int i_ = 0; i_ < 2; ++i_) {                                                \
      int r_ = w * 16 + i_ * 8 + lrow;                                              \
      gload16(Kg + (size_t)((n0) + r_) * DD + lcol, &Kb[buf][w * 1024 + i_ * 512]); \
      gload16(Vt + (size_t)r_ * NN + (n0) + lcol, &Vb[buf][w * 1024 + i_ * 512]);   \
    }                                                                               \
  }

  int cur = 0;
  STAGE(0, 0)

  for (int kv = 0; kv < NN / 64; ++kv) {
    __syncthreads();   // drains vmcnt: buf[cur] ready; fences buf reuse
    if (kv + 1 < NN / 64) STAGE(cur ^ 1, (kv + 1) * 64)

    const char* Kc = (const char*)&Kb[cur][0];
    const char* Vc = (const char*)&Vb[cur][0];
    const int xk = (l31 & 7) << 4;

#pragma unroll
    for (int sub = 0; sub < 2; ++sub) {
      // S^T = K Q^T over d=64 (4 slabs of 16)
      f32x16 s16;
#pragma unroll
      for (int i = 0; i < 16; ++i) s16[i] = 0.f;
#pragma unroll
      for (int s = 0; s < 4; ++s) {
        frag16 ka = *reinterpret_cast<const frag16*>(
            Kc + (sub * 32 + l31) * 128 + (((s * 16 + hl * 8) * 2) ^ xk));
        s16 = __builtin_amdgcn_mfma_f32_32x32x16_bf16(ka, qb[s], s16, 0, 0, 0);
      }

      // row max: in-reg tree + one cross-half exchange
      float x0 = s16[0], x1 = s16[1], x2 = s16[2], x3 = s16[3];
#pragma unroll
      for (int r = 4; r < 16; r += 4) {
        x0 = fmaxf(x0, s16[r]);
        x1 = fmaxf(x1, s16[r + 1]);
        x2 = fmaxf(x2, s16[r + 2]);
        x3 = fmaxf(x3, s16[r + 3]);
      }
      float t2 = fmaxf(fmaxf(x0, x1), fmaxf(x2, x3)) * SC;
      t2 = fmaxf(t2, __shfl_xor(t2, 32));

      // defer-max: only rescale when some row grew past THR2
      if (__any(t2 > m2 + THR2)) {
        float mnew = fmaxf(m2, t2);
        float corr = __builtin_amdgcn_exp2f(m2 - mnew);
        lsum *= corr;
#pragma unroll
        for (int r = 0; r < 16; ++r) {
          int qr = (r & 3) + 8 * (r >> 2) + 4 * hl;
          float cr = __shfl(corr, qr);
          acc0[r] *= cr;
          acc1[r] *= cr;
        }
        m2 = mnew;
      }

      // exp2 + sum (4 chains + tree + one exchange)
#pragma unroll
      for (int r = 0; r < 16; ++r)
        s16[r] = __builtin_amdgcn_exp2f(__builtin_fmaf(s16[r], SC, -m2));
      float a0 = s16[0], a1 = s16[1], a2 = s16[2], a3 = s16[3];
#pragma unroll
      for (int r = 4; r < 16; r += 4) {
        a0 += s16[r]; a1 += s16[r + 1]; a2 += s16[r + 2]; a3 += s16[r + 3];
      }
      float ss = (a0 + a1) + (a2 + a3);
      ss += __shfl_xor(ss, 32);
      lsum += ss;

      // pack P -> bf16 words; exchange with lane^32; build PV A-frags in reg
      unsigned int wv[8], xw[8];
#pragma unroll
      for (int i = 0; i < 8; ++i) wv[i] = cvt_pk_bf16(s16[2 * i], s16[2 * i + 1]);
#pragma unroll
      for (int i = 0; i < 8; ++i) xw[i] = (unsigned int)__shfl_xor((int)wv[i], 32);
      u32x4 f0v = {hl ? xw[2] : wv[0], hl ? xw[3] : wv[1], hl ? wv[2] : xw[0], hl ? wv[3] : xw[1]};
      u32x4 f1v = {hl ? xw[6] : wv[4], hl ? xw[7] : wv[5], hl ? wv[6] : xw[4], hl ? wv[7] : xw[5]};
      frag16 p0 = __builtin_bit_cast(frag16, f0v);
      frag16 p1 = __builtin_bit_cast(frag16, f1v);

      // acc += P * V  (B-frags: V^T rows from LDS, kv-contiguous)
#pragma unroll
      for (int dh = 0; dh < 2; ++dh) {
        frag16 vb0 = *reinterpret_cast<const frag16*>(
            Vc + (dh * 32 + l31) * 128 + (((sub * 32 + hl * 8) * 2) ^ xk));
        frag16 vb1 = *reinterpret_cast<const frag16*>(
            Vc + (dh * 32 + l31) * 128 + (((sub * 32 + 16 + hl * 8) * 2) ^ xk));
        f32x16& a = dh ? acc1 : acc0;
        a = __builtin_amdgcn_mfma_f32_32x32x16_bf16(p0, vb0, a, 0, 0, 0);
        a = __builtin_amdgcn_mfma_f32_32x32x16_bf16(p1, vb1, a, 0, 0, 0);
      }
    }
    cur ^= 1;
  }

  // epilogue: ctx[b*N+q][h*64+d]; normalize rows via shfl of 1/l into reg-q space
  float inv = 1.0f / lsum;
  const int b = bh / HH, h = bh - b * HH;
#pragma unroll
  for (int r = 0; r < 16; ++r) {
    int qr = (r & 3) + 8 * (r >> 2) + 4 * hl;
    float ivr = __shfl(inv, qr);
    int qn = q0 + w * 32 + qr;
    size_t base = ((size_t)(b * NN + qn)) * CC + h * DD;
    ctx[base + l31] = f2bf(acc0[r] * ivr);
    ctx[base + 32 + l31] = f2bf(acc1[r] * ivr);
  }
#undef STAGE
}

// ------------------------------------------------------------------------------
extern "C" void kernel_launch(void* const* d_in, const int* in_sizes, int n_in,
                              void* d_out, int out_size, void* d_ws, size_t ws_size,
                              hipStream_t stream) {
  const void* x = d_in[0];
  const void* qw = d_in[1];
  const void* pw = d_in[2];
  char* ws = (char*)d_ws;
  int* flag = (int*)ws;
  size_t off = 256;
  unsigned short* xb = (unsigned short*)(ws + off); off += (size_t)MTOT * CC * 2;   // reused as ctx
  unsigned short* qwb = (unsigned short*)(ws + off); off += (size_t)3 * CC * CC * 2;
  unsigned short* pwb = (unsigned short*)(ws + off); off += (size_t)CC * CC * 2;
  unsigned short* qkvbuf = (unsigned short*)(ws + off); off += (size_t)3 * MTOT * CC * 2;
  unsigned short* ctx = xb;  // x is consumed by QKV GEMM before attention writes ctx

  detect_k<<<1, 256, 0, stream>>>((const unsigned short*)x, flag);
  conv_k<<<1024, 256, 0, stream>>>(x, xb, MTOT * CC, flag);
  conv_k<<<512, 256, 0, stream>>>(qw, qwb, 3 * CC * CC, flag);
  conv_k<<<256, 256, 0, stream>>>(pw, pwb, CC * CC, flag);
  gemm_bt<0><<<dim3(MTOT / 128, (3 * CC) / 128), 256, 0, stream>>>(xb, qwb, qkvbuf, nullptr, flag);
  attn_k<<<768, 256, 0, stream>>>(qkvbuf, ctx);
  gemm_bt<1><<<dim3(MTOT / 128, CC / 128), 256, 0, stream>>>(ctx, pwb, nullptr, d_out, flag);
}